// Round 7
// baseline (348.044 us; speedup 1.0000x reference)
//
#include <hip/hip_runtime.h>

// out[b, o*8+n, h, w] = sum_k W[o,k] * x[b, n*32+k, h, w]
// B=32, C=512, HW=3136, 8 windows (stride 32, width 64), W is 64x64 f32.
//
// Per (b,n): C[64 x 3136] = W[64x64] . X[64 x 3136] via bf16 MFMA 32x32x16.
// Round 7: persistent multi-strip waves. One wave = one 224-px span of one
// (b,n) = 7 strips of 32 px, software-pipelined: while strip s computes,
// strip s+1's 32 loads are in flight (counted vmcnt, never drained to 0
// mid-loop). 98 strips/(b,n) = 14 waves x 7, zero tail. No load duplication
// (round-6 lesson), no LDS.
//
// Fragment mappings (verified by round-3/5 passes, absmax 0.0156):
//   A: lane l, elem j holds W[m*32 + (l&31)][si*16 + (l>>5)*8 + j]
//   B: lane l, elem j holds x[ch = n*32 + si*16 + (l>>5)*8 + j][px = P0+s*32+(l&31)]
//   C: col = lane&31, row = (r&3) + 8*(r>>2) + 4*(lane>>5)

#define HW   3136
#define CHW  (512 * HW)
#define NS   7          // strips per wave

typedef float  f32x16 __attribute__((ext_vector_type(16)));
typedef __bf16 bf16x8 __attribute__((ext_vector_type(8)));

__global__ __launch_bounds__(64, 3) void SKC_65841848648481_kernel(
    const float* __restrict__ x,
    const float* __restrict__ w,
    float* __restrict__ out)
{
    const int lane = threadIdx.x;
    const int lc   = lane & 31;
    const int lh   = lane >> 5;

    // Bijective XCD swizzle: 3584 work-ids, 448 contiguous per XCD
    // -> each XCD covers 4 full batches; window-overlap re-reads stay in L2.
    int id = blockIdx.x;
    id = (id & 7) * 448 + (id >> 3);
    const int wv = id % 14;          // 224-px span within (b,n)
    const int n  = (id / 14) & 7;    // window 0..7
    const int b  = id / 112;         // batch 0..31
    const int P0 = wv * 224;

    // ---- W -> A fragments (register-resident, amortized over 7 strips) ----
    bf16x8 afrag[2][4];
    #pragma unroll
    for (int m = 0; m < 2; ++m) {
        const float* wr = w + (m * 32 + lc) * 64;
        #pragma unroll
        for (int si = 0; si < 4; ++si) {
            const float4 w0 = *(const float4*)(wr + si * 16 + lh * 8);
            const float4 w1 = *(const float4*)(wr + si * 16 + lh * 8 + 4);
            bf16x8 a;
            a[0] = (__bf16)w0.x; a[1] = (__bf16)w0.y;
            a[2] = (__bf16)w0.z; a[3] = (__bf16)w0.w;
            a[4] = (__bf16)w1.x; a[5] = (__bf16)w1.y;
            a[6] = (__bf16)w1.z; a[7] = (__bf16)w1.w;
            afrag[m][si] = a;
        }
    }

    // lane's base: channel n*32 + lh*8, pixel P0 + lc  (max ch 287 < 512)
    const float* xp = x + (size_t)b * CHW + (size_t)(n * 32 + lh * 8) * HW + P0 + lc;
    float*       op = out + (size_t)b * CHW + (size_t)n * HW + P0 + lc;

    // Double-buffered per-strip x staging: 32 f32 per buffer per lane.
    float buf[2][32];

    // Prologue: issue strip 0's loads.
    #pragma unroll
    for (int q = 0; q < 32; ++q) {
        const int si = q >> 3, j = q & 7;
        buf[0][q] = xp[(size_t)(si * 16 + j) * HW];
    }

    #pragma unroll
    for (int s = 0; s < NS; ++s) {
        const int cur = s & 1;

        // Issue next strip's loads first (stay in flight under this strip's
        // pack+MFMA; compiler emits counted vmcnt for the pack below).
        if (s + 1 < NS) {
            const float* xn = xp + (s + 1) * 32;
            #pragma unroll
            for (int q = 0; q < 32; ++q) {
                const int si = q >> 3, j = q & 7;
                buf[(s + 1) & 1][q] = xn[(size_t)(si * 16 + j) * HW];
            }
        }

        // Pack + MFMA for strip s.
        f32x16 acc0, acc1;
        #pragma unroll
        for (int r = 0; r < 16; ++r) { acc0[r] = 0.0f; acc1[r] = 0.0f; }

        #pragma unroll
        for (int si = 0; si < 4; ++si) {
            bf16x8 bf;
            #pragma unroll
            for (int j = 0; j < 8; ++j)
                bf[j] = (__bf16)buf[cur][si * 8 + j];
            acc0 = __builtin_amdgcn_mfma_f32_32x32x16_bf16(
                afrag[0][si], bf, acc0, 0, 0, 0);
            acc1 = __builtin_amdgcn_mfma_f32_32x32x16_bf16(
                afrag[1][si], bf, acc1, 0, 0, 0);
        }

        // Store strip s: channel (m*32+row)*8 + n, pixel P0 + s*32 + lc.
        float* os = op + s * 32;
        #pragma unroll
        for (int r = 0; r < 16; ++r) {
            const int row = (r & 3) + 8 * (r >> 2) + 4 * lh;
            os[(size_t)(row * 8) * HW]         = acc0[r];
            os[(size_t)((32 + row) * 8) * HW]  = acc1[r];
        }
    }
}

extern "C" void kernel_launch(void* const* d_in, const int* in_sizes, int n_in,
                              void* d_out, int out_size, void* d_ws, size_t ws_size,
                              hipStream_t stream)
{
    const float* x  = (const float*)d_in[0];   // (32, 512, 56, 56) f32
    const float* w  = (const float*)d_in[1];   // (64, 64) f32
    float* out      = (float*)d_out;           // (32, 512, 56, 56) f32

    dim3 grid(14 * 8 * 32);   // one wave per 224-px span
    dim3 block(64);
    hipLaunchKernelGGL(SKC_65841848648481_kernel, grid, block, 0, stream,
                       x, w, out);
}

// Round 8
// 71.279 us; speedup vs baseline: 4.8829x; 4.8829x over previous
//
#include <hip/hip_runtime.h>

// out[b, o*8+n, h, w] = sum_k W[o,k] * x[b, n*32+k, h, w]
// B=32, C=512, HW=3136, 8 windows (stride 32, width 64), W is 64x64 f32.
//
// Round 8: LDS-staged streaming blocks (m97 pattern). Block = 448 thr (7
// waves) = half-panel (1568 px) of one (b,n); loops over 7 chunks of
// 64ch x 224px. Per chunk: 8 global_load_lds(width=16) per thread stages
// 56 KB (896 B contiguous per channel row, linear LDS dest = tid*16),
// barrier, each wave computes one 32-px tile (full M=64, K=64), stores,
// barrier. Single buffer; 56 KB -> 2 blocks/CU so sibling block's fetch
// overlaps this block's drain/compute (CU-level pipelining, no register
// staging arrays -> no scratch spill, round-7 lesson).
//
// Fragment mappings (verified rounds 3/5/6/7, absmax 0.0156):
//   A: lane l, elem j holds W[m*32 + (l&31)][si*16 + (l>>5)*8 + j]
//   B: lane l, elem j holds x[ch = n*32 + si*16 + (l>>5)*8 + j][px]
//   C: col = lane&31, row = (r&3) + 8*(r>>2) + 4*(lane>>5)

#define HW   3136
#define CHW  (512 * HW)

typedef float  f32x16 __attribute__((ext_vector_type(16)));
typedef __bf16 bf16x8 __attribute__((ext_vector_type(8)));

__global__ __launch_bounds__(448) void SKC_65841848648481_kernel(
    const float* __restrict__ x,
    const float* __restrict__ w,
    float* __restrict__ out)
{
    __shared__ float xl[64 * 224];          // [ch][px] : 56 KB

    const int tid  = threadIdx.x;
    const int lane = tid & 63;
    const int wv   = tid >> 6;              // wave 0..6 -> 32-px tile
    const int lc   = lane & 31;
    const int lh   = lane >> 5;

    // Bijective XCD swizzle: 512 ids, 64 contiguous per XCD (512 % 8 == 0)
    // -> each XCD holds 4 batches x all 8 windows; overlap re-reads L2-local.
    int id = blockIdx.x;
    id = (id & 7) * 64 + (id >> 3);
    const int h  = id & 1;                  // half-panel 0/1
    const int n  = (id >> 1) & 7;           // window 0..7
    const int b  = id >> 4;                 // batch 0..31
    const int P0 = h * 1568;                // base pixel of this half-panel

    // ---- W -> A fragments (register-resident) ----
    bf16x8 afrag[2][4];
    #pragma unroll
    for (int m = 0; m < 2; ++m) {
        const float* wr = w + (m * 32 + lc) * 64;
        #pragma unroll
        for (int si = 0; si < 4; ++si) {
            const float4 w0 = *(const float4*)(wr + si * 16 + lh * 8);
            const float4 w1 = *(const float4*)(wr + si * 16 + lh * 8 + 4);
            bf16x8 a;
            a[0] = (__bf16)w0.x; a[1] = (__bf16)w0.y;
            a[2] = (__bf16)w0.z; a[3] = (__bf16)w0.w;
            a[4] = (__bf16)w1.x; a[5] = (__bf16)w1.y;
            a[6] = (__bf16)w1.z; a[7] = (__bf16)w1.w;
            afrag[m][si] = a;
        }
    }

    // ---- staging source pointers: instr q of a chunk loads float4 at
    //      channel ch = idx/56, px-quad px4 = idx%56 (idx = q*448 + tid);
    //      LDS dest (q*448+tid)*16 bytes == xl[ch][px4*4] (224-f32 rows) ----
    const float* fp[8];
    #pragma unroll
    for (int q = 0; q < 8; ++q) {
        const int idx = q * 448 + tid;      // 0..3583
        const int ch  = idx / 56;
        const int px4 = idx - ch * 56;
        fp[q] = x + (size_t)b * CHW + (size_t)(n * 32 + ch) * HW + P0 + px4 * 4;
    }

    float* op = out + (size_t)b * CHW + (size_t)n * HW + P0 + wv * 32 + lc;

    for (int c = 0; c < 7; ++c) {
        // ---- stage chunk c: 56 KB global -> LDS, width-16 ----
        #pragma unroll
        for (int q = 0; q < 8; ++q) {
            __builtin_amdgcn_global_load_lds(
                (const __attribute__((address_space(1))) void*)(fp[q] + c * 224),
                (__attribute__((address_space(3))) void*)(&xl[(q * 448 + tid) * 4]),
                16, 0, 0);
        }
        __syncthreads();   // compiler drains vmcnt before s_barrier

        // ---- compute this wave's 32-px tile ----
        f32x16 acc0, acc1;
        #pragma unroll
        for (int r = 0; r < 16; ++r) { acc0[r] = 0.0f; acc1[r] = 0.0f; }

        #pragma unroll
        for (int si = 0; si < 4; ++si) {
            bf16x8 bf;
            #pragma unroll
            for (int j = 0; j < 8; ++j) {
                const int chl = si * 16 + lh * 8 + j;
                bf[j] = (__bf16)xl[chl * 224 + wv * 32 + lc];  // 2-way bank: free
            }
            acc0 = __builtin_amdgcn_mfma_f32_32x32x16_bf16(afrag[0][si], bf, acc0, 0, 0, 0);
            acc1 = __builtin_amdgcn_mfma_f32_32x32x16_bf16(afrag[1][si], bf, acc1, 0, 0, 0);
        }

        // ---- store: channel (m*32+row)*8 + n, pixel P0 + c*224 + wv*32 + lc ----
        float* os = op + c * 224;
        #pragma unroll
        for (int r = 0; r < 16; ++r) {
            const int row = (r & 3) + 8 * (r >> 2) + 4 * lh;
            os[(size_t)(row * 8) * HW]        = acc0[r];
            os[(size_t)((32 + row) * 8) * HW] = acc1[r];
        }
        __syncthreads();   // all LDS reads done before next chunk's staging
    }
}

extern "C" void kernel_launch(void* const* d_in, const int* in_sizes, int n_in,
                              void* d_out, int out_size, void* d_ws, size_t ws_size,
                              hipStream_t stream)
{
    const float* x  = (const float*)d_in[0];   // (32, 512, 56, 56) f32
    const float* w  = (const float*)d_in[1];   // (64, 64) f32
    float* out      = (float*)d_out;           // (32, 512, 56, 56) f32

    dim3 grid(512);    // 2 half-panels x 8 windows x 32 batches
    dim3 block(448);   // 7 waves, one 32-px tile each per chunk
    hipLaunchKernelGGL(SKC_65841848648481_kernel, grid, block, 0, stream,
                       x, w, out);
}

// Round 9
// 70.369 us; speedup vs baseline: 4.9460x; 1.0129x over previous
//
#include <hip/hip_runtime.h>

// out[b, o*8+n, h, w] = sum_k W[o,k] * x[b, n*32+k, h, w]
// B=32, C=512, HW=3136, 8 windows (stride 32, width 64), W is 64x64 f32.
//
// Round 9: R8's LDS-staged streaming + DOUBLE BUFFER, one barrier per chunk
// (T3-lite). Block = 448 thr (7 waves) owns a full (b,n) panel = 14 chunks
// of 64ch x 224px. Per chunk: issue stage(c+1) into buf^1 (8 x
// global_load_lds width-16 per thread), then compute+store chunk c from
// buf[cur], then one __syncthreads() (drains vmcnt -> stage(c+1) complete,
// all reads of buf[cur] done). Fetch of c+1 overlaps compute+store-drain of
// c, keeping HBM continuously fed. Grid 256 = 1 block/CU, LDS 112 KB.
//
// Fragment mappings (verified rounds 3/5/6/7/8, absmax 0.0156):
//   A: lane l, elem j holds W[m*32 + (l&31)][si*16 + (l>>5)*8 + j]
//   B: lane l, elem j holds x[ch = n*32 + si*16 + (l>>5)*8 + j][px]
//   C: col = lane&31, row = (r&3) + 8*(r>>2) + 4*(lane>>5)

#define HW   3136
#define CHW  (512 * HW)
#define NCHUNK 14        // 14 x 224 px = 3136

typedef float  f32x16 __attribute__((ext_vector_type(16)));
typedef __bf16 bf16x8 __attribute__((ext_vector_type(8)));

__global__ __launch_bounds__(448) void SKC_65841848648481_kernel(
    const float* __restrict__ x,
    const float* __restrict__ w,
    float* __restrict__ out)
{
    __shared__ float xl[2][64 * 224];       // 2 x 56 KB = 112 KB

    const int tid  = threadIdx.x;
    const int lane = tid & 63;
    const int wv   = tid >> 6;              // wave 0..6 -> 32-px tile in chunk
    const int lc   = lane & 31;
    const int lh   = lane >> 5;

    // Bijective XCD swizzle: 256 ids, 32 contiguous per XCD (256 % 8 == 0)
    // -> each XCD holds 4 full batches; window-overlap re-reads L2-local.
    int id = blockIdx.x;
    id = (id & 7) * 32 + (id >> 3);
    const int n = id & 7;                   // window 0..7
    const int b = id >> 3;                  // batch 0..31

    // ---- W -> A fragments (register-resident) ----
    bf16x8 afrag[2][4];
    #pragma unroll
    for (int m = 0; m < 2; ++m) {
        const float* wr = w + (m * 32 + lc) * 64;
        #pragma unroll
        for (int si = 0; si < 4; ++si) {
            const float4 w0 = *(const float4*)(wr + si * 16 + lh * 8);
            const float4 w1 = *(const float4*)(wr + si * 16 + lh * 8 + 4);
            bf16x8 a;
            a[0] = (__bf16)w0.x; a[1] = (__bf16)w0.y;
            a[2] = (__bf16)w0.z; a[3] = (__bf16)w0.w;
            a[4] = (__bf16)w1.x; a[5] = (__bf16)w1.y;
            a[6] = (__bf16)w1.z; a[7] = (__bf16)w1.w;
            afrag[m][si] = a;
        }
    }

    // ---- staging source pointers: instr q loads float4 at channel
    //      ch = idx/56, px-quad = idx%56 (idx = q*448 + tid); LDS dest
    //      (q*448+tid)*16 bytes == xl[buf][ch][px4*4] (224-f32 rows) ----
    const float* fp[8];
    #pragma unroll
    for (int q = 0; q < 8; ++q) {
        const int idx = q * 448 + tid;      // 0..3583
        const int ch  = idx / 56;
        const int px4 = idx - ch * 56;
        fp[q] = x + (size_t)b * CHW + (size_t)(n * 32 + ch) * HW + px4 * 4;
    }

    float* op = out + (size_t)b * CHW + (size_t)n * HW + wv * 32 + lc;

    // Prologue: stage chunk 0 into buf 0.
    #pragma unroll
    for (int q = 0; q < 8; ++q) {
        __builtin_amdgcn_global_load_lds(
            (const __attribute__((address_space(1))) void*)(fp[q]),
            (__attribute__((address_space(3))) void*)(&xl[0][(q * 448 + tid) * 4]),
            16, 0, 0);
    }
    __syncthreads();

    for (int c = 0; c < NCHUNK; ++c) {
        const int cur = c & 1;

        // ---- issue stage of chunk c+1 into the other buffer (in flight
        //      under this chunk's compute + store) ----
        if (c + 1 < NCHUNK) {
            #pragma unroll
            for (int q = 0; q < 8; ++q) {
                __builtin_amdgcn_global_load_lds(
                    (const __attribute__((address_space(1))) void*)(fp[q] + (c + 1) * 224),
                    (__attribute__((address_space(3))) void*)(&xl[cur ^ 1][(q * 448 + tid) * 4]),
                    16, 0, 0);
            }
        }

        // ---- compute this wave's 32-px tile of chunk c ----
        f32x16 acc0, acc1;
        #pragma unroll
        for (int r = 0; r < 16; ++r) { acc0[r] = 0.0f; acc1[r] = 0.0f; }

        #pragma unroll
        for (int si = 0; si < 4; ++si) {
            bf16x8 bf;
            #pragma unroll
            for (int j = 0; j < 8; ++j) {
                const int chl = si * 16 + lh * 8 + j;
                bf[j] = (__bf16)xl[cur][chl * 224 + wv * 32 + lc];  // 2-way bank: free
            }
            acc0 = __builtin_amdgcn_mfma_f32_32x32x16_bf16(afrag[0][si], bf, acc0, 0, 0, 0);
            acc1 = __builtin_amdgcn_mfma_f32_32x32x16_bf16(afrag[1][si], bf, acc1, 0, 0, 0);
        }

        // ---- store chunk c: channel (m*32+row)*8 + n, px c*224 + wv*32 + lc ----
        float* os = op + c * 224;
        #pragma unroll
        for (int r = 0; r < 16; ++r) {
            const int row = (r & 3) + 8 * (r >> 2) + 4 * lh;
            os[(size_t)(row * 8) * HW]        = acc0[r];
            os[(size_t)((32 + row) * 8) * HW] = acc1[r];
        }

        // One barrier per chunk: drains vmcnt (stage c+1 landed) and orders
        // all reads of buf[cur] before it's overwritten at iteration c+2.
        __syncthreads();
    }
}

extern "C" void kernel_launch(void* const* d_in, const int* in_sizes, int n_in,
                              void* d_out, int out_size, void* d_ws, size_t ws_size,
                              hipStream_t stream)
{
    const float* x  = (const float*)d_in[0];   // (32, 512, 56, 56) f32
    const float* w  = (const float*)d_in[1];   // (64, 64) f32
    float* out      = (float*)d_out;           // (32, 512, 56, 56) f32

    dim3 grid(256);    // 8 windows x 32 batches = 1 block/CU
    dim3 block(448);   // 7 waves, one 32-px tile each per chunk
    hipLaunchKernelGGL(SKC_65841848648481_kernel, grid, block, 0, stream,
                       x, w, out);
}

// Round 10
// 54.609 us; speedup vs baseline: 6.3734x; 1.2886x over previous
//
#include <hip/hip_runtime.h>

// out[b, o*8+n, h, w] = sum_k W[o,k] * x[b, n*32+k, h, w]
// B=32, C=512, HW=3136, 8 windows (stride 32, width 64), W is 64x64 f32.
//
// Round 10: R9 (LDS double-buffer, 1 barrier/chunk) + NONTEMPORAL output
// stores (isolated change). The 205 MB write-once out-stream was thrashing
// L2/L3 and evicting the window-overlap x lines (channels 32..255 are read
// by two windows); nt stores keep the out-stream from allocating in cache,
// so L3 retains x and overlap re-reads stop hitting HBM.
//
// Fragment mappings (verified rounds 3/5/6/7/8/9, absmax 0.0156):
//   A: lane l, elem j holds W[m*32 + (l&31)][si*16 + (l>>5)*8 + j]
//   B: lane l, elem j holds x[ch = n*32 + si*16 + (l>>5)*8 + j][px]
//   C: col = lane&31, row = (r&3) + 8*(r>>2) + 4*(lane>>5)

#define HW   3136
#define CHW  (512 * HW)
#define NCHUNK 14        // 14 x 224 px = 3136

typedef float  f32x16 __attribute__((ext_vector_type(16)));
typedef __bf16 bf16x8 __attribute__((ext_vector_type(8)));

__global__ __launch_bounds__(448) void SKC_65841848648481_kernel(
    const float* __restrict__ x,
    const float* __restrict__ w,
    float* __restrict__ out)
{
    __shared__ float xl[2][64 * 224];       // 2 x 56 KB = 112 KB

    const int tid  = threadIdx.x;
    const int lane = tid & 63;
    const int wv   = tid >> 6;              // wave 0..6 -> 32-px tile in chunk
    const int lc   = lane & 31;
    const int lh   = lane >> 5;

    // Bijective XCD swizzle: 256 ids, 32 contiguous per XCD (256 % 8 == 0)
    // -> each XCD holds 4 full batches; window-overlap re-reads L2-local.
    int id = blockIdx.x;
    id = (id & 7) * 32 + (id >> 3);
    const int n = id & 7;                   // window 0..7
    const int b = id >> 3;                  // batch 0..31

    // ---- W -> A fragments (register-resident) ----
    bf16x8 afrag[2][4];
    #pragma unroll
    for (int m = 0; m < 2; ++m) {
        const float* wr = w + (m * 32 + lc) * 64;
        #pragma unroll
        for (int si = 0; si < 4; ++si) {
            const float4 w0 = *(const float4*)(wr + si * 16 + lh * 8);
            const float4 w1 = *(const float4*)(wr + si * 16 + lh * 8 + 4);
            bf16x8 a;
            a[0] = (__bf16)w0.x; a[1] = (__bf16)w0.y;
            a[2] = (__bf16)w0.z; a[3] = (__bf16)w0.w;
            a[4] = (__bf16)w1.x; a[5] = (__bf16)w1.y;
            a[6] = (__bf16)w1.z; a[7] = (__bf16)w1.w;
            afrag[m][si] = a;
        }
    }

    // ---- staging source pointers: instr q loads float4 at channel
    //      ch = idx/56, px-quad = idx%56 (idx = q*448 + tid); LDS dest
    //      (q*448+tid)*16 bytes == xl[buf][ch][px4*4] (224-f32 rows) ----
    const float* fp[8];
    #pragma unroll
    for (int q = 0; q < 8; ++q) {
        const int idx = q * 448 + tid;      // 0..3583
        const int ch  = idx / 56;
        const int px4 = idx - ch * 56;
        fp[q] = x + (size_t)b * CHW + (size_t)(n * 32 + ch) * HW + px4 * 4;
    }

    float* op = out + (size_t)b * CHW + (size_t)n * HW + wv * 32 + lc;

    // Prologue: stage chunk 0 into buf 0.
    #pragma unroll
    for (int q = 0; q < 8; ++q) {
        __builtin_amdgcn_global_load_lds(
            (const __attribute__((address_space(1))) void*)(fp[q]),
            (__attribute__((address_space(3))) void*)(&xl[0][(q * 448 + tid) * 4]),
            16, 0, 0);
    }
    __syncthreads();

    for (int c = 0; c < NCHUNK; ++c) {
        const int cur = c & 1;

        // ---- issue stage of chunk c+1 into the other buffer (in flight
        //      under this chunk's compute + store) ----
        if (c + 1 < NCHUNK) {
            #pragma unroll
            for (int q = 0; q < 8; ++q) {
                __builtin_amdgcn_global_load_lds(
                    (const __attribute__((address_space(1))) void*)(fp[q] + (c + 1) * 224),
                    (__attribute__((address_space(3))) void*)(&xl[cur ^ 1][(q * 448 + tid) * 4]),
                    16, 0, 0);
            }
        }

        // ---- compute this wave's 32-px tile of chunk c ----
        f32x16 acc0, acc1;
        #pragma unroll
        for (int r = 0; r < 16; ++r) { acc0[r] = 0.0f; acc1[r] = 0.0f; }

        #pragma unroll
        for (int si = 0; si < 4; ++si) {
            bf16x8 bf;
            #pragma unroll
            for (int j = 0; j < 8; ++j) {
                const int chl = si * 16 + lh * 8 + j;
                bf[j] = (__bf16)xl[cur][chl * 224 + wv * 32 + lc];  // 2-way bank: free
            }
            acc0 = __builtin_amdgcn_mfma_f32_32x32x16_bf16(afrag[0][si], bf, acc0, 0, 0, 0);
            acc1 = __builtin_amdgcn_mfma_f32_32x32x16_bf16(afrag[1][si], bf, acc1, 0, 0, 0);
        }

        // ---- store chunk c: channel (m*32+row)*8 + n, px c*224 + wv*32 + lc
        //      NONTEMPORAL: out is write-once; don't evict x from L2/L3 ----
        float* os = op + c * 224;
        #pragma unroll
        for (int r = 0; r < 16; ++r) {
            const int row = (r & 3) + 8 * (r >> 2) + 4 * lh;
            __builtin_nontemporal_store(acc0[r], os + (size_t)(row * 8) * HW);
            __builtin_nontemporal_store(acc1[r], os + (size_t)((32 + row) * 8) * HW);
        }

        // One barrier per chunk: drains vmcnt (stage c+1 landed) and orders
        // all reads of buf[cur] before it's overwritten at iteration c+2.
        __syncthreads();
    }
}

extern "C" void kernel_launch(void* const* d_in, const int* in_sizes, int n_in,
                              void* d_out, int out_size, void* d_ws, size_t ws_size,
                              hipStream_t stream)
{
    const float* x  = (const float*)d_in[0];   // (32, 512, 56, 56) f32
    const float* w  = (const float*)d_in[1];   // (64, 64) f32
    float* out      = (float*)d_out;           // (32, 512, 56, 56) f32

    dim3 grid(256);    // 8 windows x 32 batches = 1 block/CU
    dim3 block(448);   // 7 waves, one 32-px tile each per chunk
    hipLaunchKernelGGL(SKC_65841848648481_kernel, grid, block, 0, stream,
                       x, w, out);
}